// Round 2
// baseline (952.651 us; speedup 1.0000x reference)
//
#include <hip/hip_runtime.h>

#define DDIM 2048
#define NROWS 3072

typedef float f32x4 __attribute__((ext_vector_type(4)));
typedef __bf16 bf16x8 __attribute__((ext_vector_type(8)));

__device__ __forceinline__ unsigned short f32_bf16(float f) {
    unsigned int u = __float_as_uint(f);
    u += 0x7fffu + ((u >> 16) & 1u);           // round-to-nearest-even
    return (unsigned short)(u >> 16);
}

__device__ __forceinline__ void gl2lds16(const unsigned short* g, unsigned short* l) {
    __builtin_amdgcn_global_load_lds(
        (__attribute__((address_space(1))) void*)g,
        (__attribute__((address_space(3))) void*)l, 16, 0, 0);
}

// ---- scalar prep: a = g*rsqrt(v+eps), c = be - m*a, bp init = b ----
__global__ __launch_bounds__(256) void prep_scal(
    const float* __restrict__ g1, const float* __restrict__ be1,
    const float* __restrict__ m1, const float* __restrict__ v1,
    const float* __restrict__ b1, float* __restrict__ a1, float* __restrict__ c1, float* __restrict__ bp1,
    const float* __restrict__ g3, const float* __restrict__ be3,
    const float* __restrict__ m3, const float* __restrict__ v3,
    const float* __restrict__ b3, float* __restrict__ a3, float* __restrict__ c3, float* __restrict__ bp3)
{
    int n = blockIdx.x * 256 + threadIdx.x;
    if (n < DDIM) {
        float av1 = g1[n] / sqrtf(v1[n] + 1e-3f);
        a1[n] = av1; c1[n] = be1[n] - m1[n] * av1; bp1[n] = b1[n];
        float av3 = g3[n] / sqrtf(v3[n] + 1e-3f);
        a3[n] = av3; c3[n] = be3[n] - m3[n] * av3; bp3[n] = b3[n];
    }
}

// ---- Wt[n][k] = bf16(a[k]*W[k][n]) (transpose+scale+convert) + fused bias part:
//      bp[n] += sum_k c[k]*W[k][n].  blockIdx.z selects (W1,...) vs (W3,...) ----
__global__ __launch_bounds__(256) void prep_w(
    const float* __restrict__ W1, const float* __restrict__ a1, const float* __restrict__ c1,
    unsigned short* __restrict__ Wt1, float* __restrict__ bp1,
    const float* __restrict__ W3, const float* __restrict__ a3, const float* __restrict__ c3,
    unsigned short* __restrict__ Wt3, float* __restrict__ bp3)
{
    const float* W = blockIdx.z ? W3 : W1;
    const float* a = blockIdx.z ? a3 : a1;
    const float* c = blockIdx.z ? c3 : c1;
    unsigned short* Wt = blockIdx.z ? Wt3 : Wt1;
    float* bp = blockIdx.z ? bp3 : bp1;

    __shared__ float tile[64][65];
    __shared__ float red[4][64];
    const int kt = blockIdx.x * 64, nt = blockIdx.y * 64;
    const int t = threadIdx.x;
    float part = 0.f;
#pragma unroll
    for (int q = 0; q < 16; ++q) {
        int lin = q * 256 + t;
        int r = lin >> 6, cl = lin & 63;
        float w = W[(size_t)(kt + r) * DDIM + nt + cl];
        tile[r][cl] = a[kt + r] * w;
        part += c[kt + r] * w;
    }
    red[t >> 6][t & 63] = part;
    __syncthreads();
    if (t < 64) {
        float s = red[0][t] + red[1][t] + red[2][t] + red[3][t];
        atomicAdd(&bp[nt + t], s);
    }
#pragma unroll
    for (int q = 0; q < 16; ++q) {
        int lin = q * 256 + t;
        int r = lin >> 6, cl = lin & 63;     // r: local n, cl: local k
        Wt[(size_t)(nt + r) * DDIM + kt + cl] = f32_bf16(tile[cl][r]);
    }
}

// ---- split x (float4/lane): copy o0, o5 (x[:,1:]), u2 bf16 gather ----
__global__ __launch_bounds__(256) void split_x(
    const float* __restrict__ x, float* __restrict__ o0,
    float* __restrict__ o5, unsigned short* __restrict__ u2b)
{
    int idx = blockIdx.x * 256 + threadIdx.x;            // n*1024 + i*16 + h2
    int n = idx >> 10, rem = idx & 1023, i = rem >> 4, h2 = rem & 15;
    int base = (n << 12) + (i << 6) + (h2 << 2);
    f32x4 xv = *(const f32x4*)(x + base);
    *(f32x4*)(o0 + base) = xv;
    int cc = n / 12, s = n - cc * 12;
    if (s >= 1) {
        int tb = ((cc * 11 + (s - 1)) << 12) + (i << 6) + (h2 << 2);
        *(f32x4*)(o5 + tb) = xv;
    }
    unsigned int w0, w1;
    if ((i & 1) == 0) { w0 = f32_bf16(xv[1]); w1 = f32_bf16(xv[3]); }
    else             { w0 = f32_bf16(xv[0]); w1 = f32_bf16(xv[2]); }
    *(unsigned int*)(u2b + (size_t)n * DDIM + (i << 5) + (h2 << 1)) = w0 | (w1 << 16);
}

// ---- Koopman: out[n'] = phiX[src(n')] @ kop (fp32) + bf16 w1-half emit ----
__global__ __launch_bounds__(256) void koop_k(
    const float* __restrict__ phiX, const float* __restrict__ kop,
    float* __restrict__ out, unsigned short* __restrict__ Wb)
{
    __shared__ float P[64][65];
    __shared__ alignas(16) float Kp[64][64];
    const int t = threadIdx.x;
    const int np = blockIdx.x;
    int ccp = np / 12, s = np - ccp * 12;
    int src = (((ccp & 3) << 6) + (ccp >> 2)) * 12 + s;
    const float* Ps = phiX + (size_t)src * 4096;
#pragma unroll
    for (int q = 0; q < 16; ++q) {
        int lin = q * 256 + t, r = lin >> 6, c = lin & 63;
        P[r][c] = Ps[lin];
        Kp[r][c] = kop[lin];
    }
    __syncthreads();
    const int jq = (t & 15) << 2;
    const int i0 = (t >> 4) << 2;
    f32x4 acc[4];
#pragma unroll
    for (int r = 0; r < 4; ++r) acc[r] = f32x4{0.f, 0.f, 0.f, 0.f};
    for (int k = 0; k < 64; ++k) {
        f32x4 kv = *(const f32x4*)&Kp[k][jq];
#pragma unroll
        for (int r = 0; r < 4; ++r) acc[r] += P[i0 + r][k] * kv;
    }
    float* o = out + (size_t)np * 4096;
#pragma unroll
    for (int r = 0; r < 4; ++r) {
        const int i = i0 + r;
        *(f32x4*)(o + i * 64 + jq) = acc[r];
        const int par = i & 1;
        unsigned int w0 = f32_bf16(acc[r][par]);
        unsigned int w1v = f32_bf16(acc[r][2 + par]);
        *(unsigned int*)(Wb + (size_t)np * 2048 + i * 32 + (jq >> 1)) = w0 | (w1v << 16);
    }
}

// ---- encoder GEMM (128x128, 2-barrier): C = Abf @ Wt^T(+bias), out = resid + C ----
// MODE 0 (enc g1): resid=x, PARX=0. out0=Fa f32, cb0=Mbf bf16, cb1=Dbf bf16 (w1-perm)
// MODE 1 (enc g2): resid=x, PARX=1. MIX(A=partner Fa, B=own) -> out0=o1, out1=o6 tail
template<int MODE>
__global__ __launch_bounds__(256, 3) void gemm_k(
    const unsigned short* __restrict__ Abf, const unsigned short* __restrict__ Wt,
    const float* __restrict__ bp, const float* __restrict__ resid0,
    float* __restrict__ out0, float* __restrict__ out1,
    unsigned short* __restrict__ cb0, unsigned short* __restrict__ cb1,
    const float* __restrict__ partner)
{
    constexpr int PARX = (MODE == 1) ? 1 : 0;

    __shared__ alignas(16) unsigned short As[128][64];
    __shared__ alignas(16) unsigned short Bs[128][64];
    const int t = threadIdx.x;
    const int lane = t & 63, wave = t >> 6;
    const int quad = lane >> 4, l16 = lane & 15;
    // XCD-bijective swizzle: 384 blocks, 8 XCDs -> 48 consecutive per XCD (2 n-cols)
    const int id = blockIdx.x;
    const int swz = (id & 7) * 48 + (id >> 3);
    const int m0 = (swz % 24) << 7;
    const int n0 = (swz / 24) << 7;
    const int wm = (wave >> 1) << 6;
    const int wn = (wave & 1) << 6;

    const int srow = lane >> 3;
    const int cdata = (lane & 7) ^ srow;
    const unsigned short* Ag = Abf + (size_t)(m0 + wave * 32 + srow) * DDIM + (cdata << 3);
    const unsigned short* Bg = Wt  + (size_t)(n0 + wave * 32 + srow) * DDIM + (cdata << 3);
    unsigned short* AslBase = &As[wave * 32][0];
    unsigned short* BslBase = &Bs[wave * 32][0];

    f32x4 acc[4][4];
#pragma unroll
    for (int a = 0; a < 4; ++a)
#pragma unroll
        for (int b = 0; b < 4; ++b) acc[a][b] = f32x4{0.f, 0.f, 0.f, 0.f};

    for (int k0 = 0; k0 < DDIM; k0 += 64) {
        __syncthreads();
#pragma unroll
        for (int j = 0; j < 4; ++j) {
            gl2lds16(Ag + (size_t)(j * 8) * DDIM + k0, AslBase + j * 8 * 64);
            gl2lds16(Bg + (size_t)(j * 8) * DDIM + k0, BslBase + j * 8 * 64);
        }
        __syncthreads();

#pragma unroll
        for (int kk = 0; kk < 2; ++kk) {
            bf16x8 af[4], bfr[4];
#pragma unroll
            for (int mi = 0; mi < 4; ++mi) {
                const int r = wm + mi * 16 + l16;
                af[mi] = *(const bf16x8*)&As[r][(((kk << 2) | quad) ^ (l16 & 7)) << 3];
            }
#pragma unroll
            for (int ni = 0; ni < 4; ++ni) {
                const int r = wn + ni * 16 + l16;
                bfr[ni] = *(const bf16x8*)&Bs[r][(((kk << 2) | quad) ^ (l16 & 7)) << 3];
            }
#pragma unroll
            for (int mi = 0; mi < 4; ++mi)
#pragma unroll
                for (int ni = 0; ni < 4; ++ni)
                    acc[mi][ni] = __builtin_amdgcn_mfma_f32_16x16x32_bf16(
                        af[mi], bfr[ni], acc[mi][ni], 0, 0, 0);
        }
    }

#pragma unroll
    for (int ni = 0; ni < 4; ++ni) {
        const int n = n0 + wn + ni * 16 + l16;
        const float bias = bp[n];
        const int i = n >> 5, h = n & 31;
        const int par = (i & 1) ^ PARX;
#pragma unroll
        for (int mi = 0; mi < 4; ++mi) {
            const int mbase = m0 + wm + mi * 16 + (quad << 2);
#pragma unroll
            for (int r = 0; r < 4; ++r) {
                const int mm = mbase + r;
                float cv = acc[mi][ni][r] + bias;
                float rs = resid0[((size_t)mm << 12) + (i << 6) + (h << 1) + par];
                float o = rs + cv;
                if constexpr (MODE == 0) {
                    out0[(size_t)mm * DDIM + n] = o;
                    unsigned short us = f32_bf16(o);
                    cb0[(size_t)mm * DDIM + n] = us;
                    const int hw = (h - (i & 1)) & 31;
                    cb1[(size_t)mm * DDIM + (i << 5) + hw] = us;
                } else {
                    float2 f2; int col;
                    if ((i & 1) == 0) {
                        col = h << 1;
                        f2.x = partner[(size_t)mm * DDIM + n];
                        f2.y = o;
                    } else {
                        col = ((h + 1) & 31) << 1;
                        f2.x = o;
                        f2.y = partner[(size_t)mm * DDIM + (i << 5) + ((h + 2) & 31)];
                    }
                    *(float2*)(out0 + ((size_t)mm << 12) + (i << 6) + col) = f2;
                    int cc = mm / 12, s = mm - cc * 12;
                    if (s >= 1)
                        *(float2*)(out1 + (((size_t)(cc * 11 + s - 1) << 12) + (i << 6) + col)) = f2;
                }
            }
        }
    }
}

// ---- decoder GEMM: 256x256 tile, BK=64, 8 waves, 8-phase counted-vmcnt pipeline ----
// LDS (dynamic 128KiB): S[2 buf][4 slot][256 rows][32 bf16]; slots {A-k0,B-k0,A-k1,B-k1}.
// Phase p of K-tile T: ds_read frags (kk=p>>1, M-half=p&1) from buf[T&1];
// stage slot p of tile T+1 into buf[~T&1] (lead 4 phases); vmcnt(4) ckpt at p=0,2.
// MODE 2 (dec g1): resid=o1/o3, PARX=1, out = rs - cv. out0=Ga f32, cb0=Gbf bf16
// MODE 3 (dec g2): resid=o1/o3, PARX=0. MIX(A=own u1, B=partner Ga) -> out0=o2 / out1=o4
template<int MODE>
__global__ __launch_bounds__(512, 2) void gemm256_k(
    const unsigned short* __restrict__ Abf, const unsigned short* __restrict__ Wt,
    const float* __restrict__ bp, const float* __restrict__ resid0, const float* __restrict__ resid1,
    float* __restrict__ out0, float* __restrict__ out1,
    unsigned short* __restrict__ cb0, const float* __restrict__ partner)
{
    constexpr int PARX = (MODE == 2) ? 1 : 0;
    extern __shared__ unsigned short S[];     // 2*4*256*32 = 65536 ush = 128 KiB

    const int t = threadIdx.x;
    const int lane = t & 63, wave = t >> 6;
    const int quad = lane >> 4, l16 = lane & 15;
    const int wm = wave >> 2, wn = wave & 3;  // 2M x 4N wave grid, wave tile 128x64
    // XCD-bijective swizzle: 192 blocks -> 24 per XCD = one full n-column each
    const int id = blockIdx.x;
    const int swz = (id & 7) * 24 + (id >> 3);
    const int m0 = (swz % 24) << 8;
    const int n0 = (swz / 24) << 8;

    // staging: per gl2lds, lane L -> row (L>>2), kchunk (L&3); 2 insts = 32 rows/wave
    const int srow = lane >> 2, schunk = lane & 3;
    const unsigned short* Ag = Abf + (size_t)(m0 + wave * 32 + srow) * DDIM + schunk * 8;
    const unsigned short* Bg = Wt  + (size_t)(n0 + wave * 32 + srow) * DDIM + schunk * 8;

    f32x4 acc[8][4];
#pragma unroll
    for (int a = 0; a < 8; ++a)
#pragma unroll
        for (int b = 0; b < 4; ++b) acc[a][b] = f32x4{0.f, 0.f, 0.f, 0.f};

    auto stage = [&](int buf, int slot, const unsigned short* g, int koff) __attribute__((always_inline)) {
        unsigned short* d = &S[(((buf << 2) | slot) << 13) + wave * 1024];
        gl2lds16(g + koff, d);
        gl2lds16(g + koff + 16 * DDIM, d + 512);
    };
    auto phase_mfma = [&](int buf, int kk, int H) __attribute__((always_inline)) {
        bf16x8 a_[4], b_[4];
        const int sa = (((buf << 2) | (kk << 1)) << 13) + (wm * 128 + H * 64 + l16) * 32 + quad * 8;
        const int sb = ((((buf << 2) | (kk << 1)) | 1) << 13) + (wn * 64 + l16) * 32 + quad * 8;
#pragma unroll
        for (int mi = 0; mi < 4; ++mi) a_[mi] = *(const bf16x8*)&S[sa + mi * 512];
#pragma unroll
        for (int ni = 0; ni < 4; ++ni) b_[ni] = *(const bf16x8*)&S[sb + ni * 512];
        __builtin_amdgcn_s_setprio(1);
#pragma unroll
        for (int mi = 0; mi < 4; ++mi)
#pragma unroll
            for (int ni = 0; ni < 4; ++ni)
                acc[H * 4 + mi][ni] = __builtin_amdgcn_mfma_f32_16x16x32_bf16(
                    a_[mi], b_[ni], acc[H * 4 + mi][ni], 0, 0, 0);
        __builtin_amdgcn_s_setprio(0);
    };

    // prologue: tile 0 -> buf 0
    stage(0, 0, Ag, 0);
    stage(0, 1, Bg, 0);
    stage(0, 2, Ag, 32);
    stage(0, 3, Bg, 32);

    for (int T = 0; T < 31; ++T) {
        const int buf = T & 1, nb = buf ^ 1;
        const int kt = (T + 1) * 64;
        asm volatile("s_waitcnt vmcnt(4)" ::: "memory");   // slots 0,1 of T landed
        __builtin_amdgcn_s_barrier();
        __builtin_amdgcn_sched_barrier(0);
        stage(nb, 0, Ag, kt);
        phase_mfma(buf, 0, 0);
        __builtin_amdgcn_s_barrier();
        __builtin_amdgcn_sched_barrier(0);
        stage(nb, 1, Bg, kt);
        phase_mfma(buf, 0, 1);
        asm volatile("s_waitcnt vmcnt(4)" ::: "memory");   // slots 2,3 of T landed
        __builtin_amdgcn_s_barrier();
        __builtin_amdgcn_sched_barrier(0);
        stage(nb, 2, Ag, kt + 32);
        phase_mfma(buf, 1, 0);
        __builtin_amdgcn_s_barrier();
        __builtin_amdgcn_sched_barrier(0);
        stage(nb, 3, Bg, kt + 32);
        phase_mfma(buf, 1, 1);
    }
    // peeled last tile (T=31, buf=1): nothing newer issued -> p2 must drain
    asm volatile("s_waitcnt vmcnt(4)" ::: "memory");
    __builtin_amdgcn_s_barrier(); __builtin_amdgcn_sched_barrier(0);
    phase_mfma(1, 0, 0);
    __builtin_amdgcn_s_barrier(); __builtin_amdgcn_sched_barrier(0);
    phase_mfma(1, 0, 1);
    asm volatile("s_waitcnt vmcnt(0)" ::: "memory");
    __builtin_amdgcn_s_barrier(); __builtin_amdgcn_sched_barrier(0);
    phase_mfma(1, 1, 0);
    __builtin_amdgcn_s_barrier(); __builtin_amdgcn_sched_barrier(0);
    phase_mfma(1, 1, 1);

    // ---- fused epilogue ----
    const bool second = (m0 >= NROWS);
#pragma unroll
    for (int ni = 0; ni < 4; ++ni) {
        const int n = n0 + wn * 64 + ni * 16 + l16;
        const float bias = bp[n];
        const int i = n >> 5, h = n & 31;
        const int par = (i & 1) ^ PARX;
#pragma unroll
        for (int a = 0; a < 8; ++a) {
            const int mbase = m0 + wm * 128 + (a >> 2) * 64 + (a & 3) * 16 + (quad << 2);
#pragma unroll
            for (int r = 0; r < 4; ++r) {
                const int mm = mbase + r;
                const int mloc = second ? (mm - NROWS) : mm;
                float cv = acc[a][ni][r] + bias;
                const float* rrow = (second ? resid1 : resid0) + ((size_t)mloc << 12);
                float rs = rrow[(i << 6) + (h << 1) + par];
                float o = rs - cv;
                if constexpr (MODE == 2) {
                    out0[(size_t)mm * DDIM + n] = o;
                    cb0[(size_t)mm * DDIM + n] = f32_bf16(o);
                } else {
                    float2 f2; int col;
                    if ((i & 1) == 0) {
                        col = h << 1;
                        f2.x = o;                                       // A[h] (own u1)
                        f2.y = partner[(size_t)mm * DDIM + n];          // B[h] (v2)
                    } else {
                        col = ((h + 31) & 31) << 1;
                        f2.x = partner[(size_t)mm * DDIM + (i << 5) + ((h + 30) & 31)];
                        f2.y = o;
                    }
                    float* yb = second ? out1 : out0;
                    *(float2*)(yb + ((size_t)mloc << 12) + (i << 6) + col) = f2;
                }
            }
        }
    }
}

extern "C" void kernel_launch(void* const* d_in, const int* in_sizes, int n_in,
                              void* d_out, int out_size, void* d_ws, size_t ws_size,
                              hipStream_t stream)
{
    (void)in_sizes; (void)n_in; (void)out_size; (void)ws_size;
    const float* x   = (const float*)d_in[0];
    const float* W1  = (const float*)d_in[2];
    const float* b1  = (const float*)d_in[3];
    const float* g1  = (const float*)d_in[4];
    const float* be1 = (const float*)d_in[5];
    const float* m1  = (const float*)d_in[6];
    const float* v1i = (const float*)d_in[7];
    const float* W3  = (const float*)d_in[8];
    const float* b3  = (const float*)d_in[9];
    const float* g3  = (const float*)d_in[10];
    const float* be3 = (const float*)d_in[11];
    const float* m3  = (const float*)d_in[12];
    const float* v3i = (const float*)d_in[13];
    const float* kop = (const float*)d_in[14];

    float* out = (float*)d_out;
    float* o0 = out;                 // x
    float* o1 = out + 12582912;      // phiX
    float* o2 = out + 25165824;      // dephiPhiX
    float* o3 = out + 37748736;      // kPhix
    float* o4 = out + 50331648;      // dePhiKPhiX
    float* o5 = out + 62914560;      // x[:,1:]
    float* o6 = out + 74448896;      // phiX[:,1:]

    char* ws = (char*)d_ws;
    float* a1  = (float*)(ws);
    float* c1  = (float*)(ws + 8192);
    float* a3  = (float*)(ws + 16384);
    float* c3  = (float*)(ws + 24576);
    float* bp1 = (float*)(ws + 32768);
    float* bp3 = (float*)(ws + 40960);
    unsigned short* Wt1 = (unsigned short*)(ws + 49152);
    unsigned short* Wt3 = (unsigned short*)(ws + 8437760);
    unsigned short* Abf = (unsigned short*)(ws + 16826368);   // u2 bf16 (enc g1 A)
    unsigned short* Mbf = (unsigned short*)(ws + 29409280);   // v1 bf16 (enc g2 A)
    unsigned short* Dbf = (unsigned short*)(ws + 41992192);   // w1(phiX) bf16  \ adjacent ->
    unsigned short* Kbf = (unsigned short*)(ws + 54575104);   // w1(kPhix) bf16 / [6144,2048] A for dec g1
    float* Fa  = (float*)(ws + 67158016);                     // v1 f32 (enc mix partner)
    float* Ga  = (float*)(ws + 67158016);                     // [6144,2048] v2 f32 (aliases Fa; Fa dead)
    unsigned short* Gbf = (unsigned short*)(ws + 16826368);   // [6144,2048] v2 bf16 (aliases Abf+Mbf; dead)

    static bool attr_set = false;
    if (!attr_set) {
        hipFuncSetAttribute(reinterpret_cast<const void*>(gemm256_k<2>),
                            hipFuncAttributeMaxDynamicSharedMemorySize, 131072);
        hipFuncSetAttribute(reinterpret_cast<const void*>(gemm256_k<3>),
                            hipFuncAttributeMaxDynamicSharedMemorySize, 131072);
        attr_set = true;
    }

    prep_scal<<<8, 256, 0, stream>>>(g1, be1, m1, v1i, b1, a1, c1, bp1,
                                     g3, be3, m3, v3i, b3, a3, c3, bp3);
    prep_w<<<dim3(32, 32, 2), 256, 0, stream>>>(W1, a1, c1, Wt1, bp1,
                                                W3, a3, c3, Wt3, bp3);
    split_x<<<12288, 256, 0, stream>>>(x, o0, o5, Abf);

    // encoder (128^2): v1 = u1 + u2@W1' ; w2 = u2 + v1@W3' ; phiX = mix(v1,w2) fused
    gemm_k<0><<<384, 256, 0, stream>>>(Abf, Wt1, bp1, x, Fa, nullptr, Mbf, Dbf, nullptr);
    gemm_k<1><<<384, 256, 0, stream>>>(Mbf, Wt3, bp3, x, o1, o6, nullptr, nullptr, Fa);

    // koopman (emits Kbf := w1(kPhix) bf16)
    koop_k<<<3072, 256, 0, stream>>>(o1, kop, o3, Kbf);

    // batched decoders (256^2 8-phase): v2 = w2 - w1@W3' ; u1 = w1 - v2@W1' ; mix fused
    gemm256_k<2><<<192, 512, 131072, stream>>>(Dbf, Wt3, bp3, o1, o3, Ga, nullptr, Gbf, nullptr);
    gemm256_k<3><<<192, 512, 131072, stream>>>(Gbf, Wt1, bp1, o1, o3, o2, o4, nullptr, Ga);
}

// Round 4
// 865.739 us; speedup vs baseline: 1.1004x; 1.1004x over previous
//
#include <hip/hip_runtime.h>

#define DDIM 2048
#define NROWS 3072

typedef float f32x4 __attribute__((ext_vector_type(4)));
typedef __bf16 bf16x8 __attribute__((ext_vector_type(8)));

__device__ __forceinline__ unsigned short f32_bf16(float f) {
    unsigned int u = __float_as_uint(f);
    u += 0x7fffu + ((u >> 16) & 1u);           // round-to-nearest-even
    return (unsigned short)(u >> 16);
}

__device__ __forceinline__ void gl2lds16(const unsigned short* g, unsigned short* l) {
    __builtin_amdgcn_global_load_lds(
        (__attribute__((address_space(1))) void*)g,
        (__attribute__((address_space(3))) void*)l, 16, 0, 0);
}

// ---- scalar prep: a = g*rsqrt(v+eps), c = be - m*a, bp init = b ----
__global__ __launch_bounds__(256) void prep_scal(
    const float* __restrict__ g1, const float* __restrict__ be1,
    const float* __restrict__ m1, const float* __restrict__ v1,
    const float* __restrict__ b1, float* __restrict__ a1, float* __restrict__ c1, float* __restrict__ bp1,
    const float* __restrict__ g3, const float* __restrict__ be3,
    const float* __restrict__ m3, const float* __restrict__ v3,
    const float* __restrict__ b3, float* __restrict__ a3, float* __restrict__ c3, float* __restrict__ bp3)
{
    int n = blockIdx.x * 256 + threadIdx.x;
    if (n < DDIM) {
        float av1 = g1[n] / sqrtf(v1[n] + 1e-3f);
        a1[n] = av1; c1[n] = be1[n] - m1[n] * av1; bp1[n] = b1[n];
        float av3 = g3[n] / sqrtf(v3[n] + 1e-3f);
        a3[n] = av3; c3[n] = be3[n] - m3[n] * av3; bp3[n] = b3[n];
    }
}

// ---- Wt[n][k] = bf16(a[k]*W[k][n]) (transpose+scale+convert) + fused bias part:
//      bp[n] += sum_k c[k]*W[k][n].  blockIdx.z selects (W1,...) vs (W3,...) ----
__global__ __launch_bounds__(256) void prep_w(
    const float* __restrict__ W1, const float* __restrict__ a1, const float* __restrict__ c1,
    unsigned short* __restrict__ Wt1, float* __restrict__ bp1,
    const float* __restrict__ W3, const float* __restrict__ a3, const float* __restrict__ c3,
    unsigned short* __restrict__ Wt3, float* __restrict__ bp3)
{
    const float* W = blockIdx.z ? W3 : W1;
    const float* a = blockIdx.z ? a3 : a1;
    const float* c = blockIdx.z ? c3 : c1;
    unsigned short* Wt = blockIdx.z ? Wt3 : Wt1;
    float* bp = blockIdx.z ? bp3 : bp1;

    __shared__ float tile[64][65];
    __shared__ float red[4][64];
    const int kt = blockIdx.x * 64, nt = blockIdx.y * 64;
    const int t = threadIdx.x;
    float part = 0.f;
#pragma unroll
    for (int q = 0; q < 16; ++q) {
        int lin = q * 256 + t;
        int r = lin >> 6, cl = lin & 63;
        float w = W[(size_t)(kt + r) * DDIM + nt + cl];
        tile[r][cl] = a[kt + r] * w;
        part += c[kt + r] * w;
    }
    red[t >> 6][t & 63] = part;
    __syncthreads();
    if (t < 64) {
        float s = red[0][t] + red[1][t] + red[2][t] + red[3][t];
        atomicAdd(&bp[nt + t], s);
    }
#pragma unroll
    for (int q = 0; q < 16; ++q) {
        int lin = q * 256 + t;
        int r = lin >> 6, cl = lin & 63;     // r: local n, cl: local k
        Wt[(size_t)(nt + r) * DDIM + kt + cl] = f32_bf16(tile[cl][r]);
    }
}

// ---- split x (float4/lane): copy o0, o5 (x[:,1:]), u2 bf16 gather ----
__global__ __launch_bounds__(256) void split_x(
    const float* __restrict__ x, float* __restrict__ o0,
    float* __restrict__ o5, unsigned short* __restrict__ u2b)
{
    int idx = blockIdx.x * 256 + threadIdx.x;            // n*1024 + i*16 + h2
    int n = idx >> 10, rem = idx & 1023, i = rem >> 4, h2 = rem & 15;
    int base = (n << 12) + (i << 6) + (h2 << 2);
    f32x4 xv = *(const f32x4*)(x + base);
    *(f32x4*)(o0 + base) = xv;
    int cc = n / 12, s = n - cc * 12;
    if (s >= 1) {
        int tb = ((cc * 11 + (s - 1)) << 12) + (i << 6) + (h2 << 2);
        *(f32x4*)(o5 + tb) = xv;
    }
    unsigned int w0, w1;
    if ((i & 1) == 0) { w0 = f32_bf16(xv[1]); w1 = f32_bf16(xv[3]); }
    else             { w0 = f32_bf16(xv[0]); w1 = f32_bf16(xv[2]); }
    *(unsigned int*)(u2b + (size_t)n * DDIM + (i << 5) + (h2 << 1)) = w0 | (w1 << 16);
}

// ---- Koopman: out[n'] = phiX[src(n')] @ kop (fp32) + bf16 w1-half emit ----
__global__ __launch_bounds__(256) void koop_k(
    const float* __restrict__ phiX, const float* __restrict__ kop,
    float* __restrict__ out, unsigned short* __restrict__ Wb)
{
    __shared__ float P[64][65];
    __shared__ alignas(16) float Kp[64][64];
    const int t = threadIdx.x;
    const int np = blockIdx.x;
    int ccp = np / 12, s = np - ccp * 12;
    int src = (((ccp & 3) << 6) + (ccp >> 2)) * 12 + s;
    const float* Ps = phiX + (size_t)src * 4096;
#pragma unroll
    for (int q = 0; q < 16; ++q) {
        int lin = q * 256 + t, r = lin >> 6, c = lin & 63;
        P[r][c] = Ps[lin];
        Kp[r][c] = kop[lin];
    }
    __syncthreads();
    const int jq = (t & 15) << 2;
    const int i0 = (t >> 4) << 2;
    f32x4 acc[4];
#pragma unroll
    for (int r = 0; r < 4; ++r) acc[r] = f32x4{0.f, 0.f, 0.f, 0.f};
    for (int k = 0; k < 64; ++k) {
        f32x4 kv = *(const f32x4*)&Kp[k][jq];
#pragma unroll
        for (int r = 0; r < 4; ++r) acc[r] += P[i0 + r][k] * kv;
    }
    float* o = out + (size_t)np * 4096;
#pragma unroll
    for (int r = 0; r < 4; ++r) {
        const int i = i0 + r;
        *(f32x4*)(o + i * 64 + jq) = acc[r];
        const int par = i & 1;
        unsigned int w0 = f32_bf16(acc[r][par]);
        unsigned int w1v = f32_bf16(acc[r][2 + par]);
        *(unsigned int*)(Wb + (size_t)np * 2048 + i * 32 + (jq >> 1)) = w0 | (w1v << 16);
    }
}

// ---- main GEMM (128x128, 2-barrier, XOR-8 LDS, XCD-swizzled grid) ----
// C = Abf @ Wt^T(+bias), out = resid +/- C, fused epilogues.
// MODE 0 (enc g1): M=3072, +, resid=x.  out0=Fa f32, cb0=Mbf bf16, cb1=Dbf bf16 (w1-perm)
// MODE 1 (enc g2): M=3072, +, resid=x.  MIX(A=partner Fa, B=own) -> out0=o1, out1=o6 tail
// MODE 2 (dec g1): M=6144, -, resid=o1/o3. out0=Ga f32, cb0=Gbf bf16
// MODE 3 (dec g2): M=6144, -, resid=o1/o3. MIX(A=own, B=partner Ga) -> out0=o2, out1=o4
template<int MODE>
__global__ __launch_bounds__(256, 3) void gemm_k(
    const unsigned short* __restrict__ Abf, const unsigned short* __restrict__ Wt,
    const float* __restrict__ bp, const float* __restrict__ resid0, const float* __restrict__ resid1,
    float* __restrict__ out0, float* __restrict__ out1,
    unsigned short* __restrict__ cb0, unsigned short* __restrict__ cb1,
    const float* __restrict__ partner)
{
    constexpr int PARX = (MODE == 1 || MODE == 2) ? 1 : 0;
    constexpr bool NEG  = (MODE >= 2);
    constexpr bool DUAL = (MODE >= 2);
    constexpr int MT  = DUAL ? 48 : 24;    // m-tiles
    constexpr int CPX = DUAL ? 96 : 48;    // blocks per XCD (grid/8, both %8==0 -> bijective)

    __shared__ alignas(16) unsigned short As[128][64];
    __shared__ alignas(16) unsigned short Bs[128][64];
    const int t = threadIdx.x;
    const int lane = t & 63, wave = t >> 6;
    const int quad = lane >> 4, l16 = lane & 15;
    const int id = blockIdx.x;
    const int swz = (id & 7) * CPX + (id >> 3);   // XCD-contiguous chunk, m-major
    const int m0 = (swz % MT) << 7;
    const int n0 = (swz / MT) << 7;
    const int wm = (wave >> 1) << 6;   // 0 / 64
    const int wn = (wave & 1) << 6;    // 0 / 64

    const int srow = lane >> 3;
    const int cdata = (lane & 7) ^ srow;        // XOR swizzle (row&7 == srow&7)
    const unsigned short* Ag = Abf + (size_t)(m0 + wave * 32 + srow) * DDIM + (cdata << 3);
    const unsigned short* Bg = Wt  + (size_t)(n0 + wave * 32 + srow) * DDIM + (cdata << 3);
    unsigned short* AslBase = &As[wave * 32][0];
    unsigned short* BslBase = &Bs[wave * 32][0];

    f32x4 acc[4][4];
#pragma unroll
    for (int a = 0; a < 4; ++a)
#pragma unroll
        for (int b = 0; b < 4; ++b) acc[a][b] = f32x4{0.f, 0.f, 0.f, 0.f};

    for (int k0 = 0; k0 < DDIM; k0 += 64) {
        __syncthreads();                        // prior tile's frag reads done
#pragma unroll
        for (int j = 0; j < 4; ++j) {
            gl2lds16(Ag + (size_t)(j * 8) * DDIM + k0, AslBase + j * 8 * 64);
            gl2lds16(Bg + (size_t)(j * 8) * DDIM + k0, BslBase + j * 8 * 64);
        }
        __syncthreads();                        // staged (vmcnt drained by compiler)

#pragma unroll
        for (int kk = 0; kk < 2; ++kk) {
            bf16x8 af[4], bfr[4];
#pragma unroll
            for (int mi = 0; mi < 4; ++mi) {
                const int r = wm + mi * 16 + l16;
                af[mi] = *(const bf16x8*)&As[r][(((kk << 2) | quad) ^ (l16 & 7)) << 3];
            }
#pragma unroll
            for (int ni = 0; ni < 4; ++ni) {
                const int r = wn + ni * 16 + l16;
                bfr[ni] = *(const bf16x8*)&Bs[r][(((kk << 2) | quad) ^ (l16 & 7)) << 3];
            }
#pragma unroll
            for (int mi = 0; mi < 4; ++mi)
#pragma unroll
                for (int ni = 0; ni < 4; ++ni)
                    acc[mi][ni] = __builtin_amdgcn_mfma_f32_16x16x32_bf16(
                        af[mi], bfr[ni], acc[mi][ni], 0, 0, 0);
        }
    }

    const bool second = DUAL && (m0 >= NROWS);

    // epilogue: D element (row=quad*4+r, col=l16) per 16x16 tile
#pragma unroll
    for (int ni = 0; ni < 4; ++ni) {
        const int n = n0 + wn + ni * 16 + l16;
        const float bias = bp[n];
        const int i = n >> 5, h = n & 31;
        const int par = (i & 1) ^ PARX;
#pragma unroll
        for (int mi = 0; mi < 4; ++mi) {
            const int mbase = m0 + wm + mi * 16 + (quad << 2);
#pragma unroll
            for (int r = 0; r < 4; ++r) {
                const int mm = mbase + r;
                const int mloc = second ? (mm - NROWS) : mm;
                float cv = acc[mi][ni][r] + bias;
                const float* rrow = (DUAL ? (second ? resid1 : resid0) : resid0)
                                    + ((size_t)(DUAL ? mloc : mm) << 12);
                float rs = rrow[(i << 6) + (h << 1) + par];
                float o = NEG ? (rs - cv) : (rs + cv);
                if constexpr (MODE == 0) {
                    out0[(size_t)mm * DDIM + n] = o;
                    unsigned short us = f32_bf16(o);
                    cb0[(size_t)mm * DDIM + n] = us;
                    // w1(phiX)[i][hw] = v1[i][(hw+(i&1))&31]  ->  hw = (h-(i&1))&31
                    const int hw = (h - (i & 1)) & 31;
                    cb1[(size_t)mm * DDIM + (i << 5) + hw] = us;
                } else if constexpr (MODE == 2) {
                    out0[(size_t)mm * DDIM + n] = o;
                    cb0[(size_t)mm * DDIM + n] = f32_bf16(o);
                } else if constexpr (MODE == 1) {
                    // mix: A = partner (v1=Fa), B = own (w2)
                    float2 f2; int col;
                    if ((i & 1) == 0) {
                        col = h << 1;
                        f2.x = partner[(size_t)mm * DDIM + n];          // A[h]
                        f2.y = o;                                       // B[h]
                    } else {
                        col = ((h + 1) & 31) << 1;                      // own lands at y[2h']
                        f2.x = o;                                       // B[(h'-1)%32]
                        f2.y = partner[(size_t)mm * DDIM + (i << 5) + ((h + 2) & 31)]; // A[(h'+1)%32]
                    }
                    *(float2*)(out0 + ((size_t)mm << 12) + (i << 6) + col) = f2;
                    int cc = mm / 12, s = mm - cc * 12;
                    if (s >= 1)
                        *(float2*)(out1 + (((size_t)(cc * 11 + s - 1) << 12) + (i << 6) + col)) = f2;
                } else {
                    // MODE 3 mix: A = own (u1), B = partner (v2=Ga)
                    float2 f2; int col;
                    if ((i & 1) == 0) {
                        col = h << 1;
                        f2.x = o;                                       // A[h]
                        f2.y = partner[(size_t)mm * DDIM + n];          // B[h]
                    } else {
                        col = ((h + 31) & 31) << 1;                     // own at y[2h'+1]
                        f2.x = partner[(size_t)mm * DDIM + (i << 5) + ((h + 30) & 31)]; // B[(h'-1)%32]
                        f2.y = o;
                    }
                    float* yb = second ? out1 : out0;
                    *(float2*)(yb + ((size_t)mloc << 12) + (i << 6) + col) = f2;
                }
            }
        }
    }
}

extern "C" void kernel_launch(void* const* d_in, const int* in_sizes, int n_in,
                              void* d_out, int out_size, void* d_ws, size_t ws_size,
                              hipStream_t stream)
{
    (void)in_sizes; (void)n_in; (void)out_size; (void)ws_size;
    const float* x   = (const float*)d_in[0];
    const float* W1  = (const float*)d_in[2];
    const float* b1  = (const float*)d_in[3];
    const float* g1  = (const float*)d_in[4];
    const float* be1 = (const float*)d_in[5];
    const float* m1  = (const float*)d_in[6];
    const float* v1i = (const float*)d_in[7];
    const float* W3  = (const float*)d_in[8];
    const float* b3  = (const float*)d_in[9];
    const float* g3  = (const float*)d_in[10];
    const float* be3 = (const float*)d_in[11];
    const float* m3  = (const float*)d_in[12];
    const float* v3i = (const float*)d_in[13];
    const float* kop = (const float*)d_in[14];

    float* out = (float*)d_out;
    float* o0 = out;                 // x
    float* o1 = out + 12582912;      // phiX
    float* o2 = out + 25165824;      // dephiPhiX
    float* o3 = out + 37748736;      // kPhix
    float* o4 = out + 50331648;      // dePhiKPhiX
    float* o5 = out + 62914560;      // x[:,1:]
    float* o6 = out + 74448896;      // phiX[:,1:]

    char* ws = (char*)d_ws;
    float* a1  = (float*)(ws);
    float* c1  = (float*)(ws + 8192);
    float* a3  = (float*)(ws + 16384);
    float* c3  = (float*)(ws + 24576);
    float* bp1 = (float*)(ws + 32768);
    float* bp3 = (float*)(ws + 40960);
    unsigned short* Wt1 = (unsigned short*)(ws + 49152);
    unsigned short* Wt3 = (unsigned short*)(ws + 8437760);
    unsigned short* Abf = (unsigned short*)(ws + 16826368);   // u2 bf16 (enc g1 A)
    unsigned short* Mbf = (unsigned short*)(ws + 29409280);   // v1 bf16 (enc g2 A)
    unsigned short* Dbf = (unsigned short*)(ws + 41992192);   // w1(phiX) bf16  \ adjacent ->
    unsigned short* Kbf = (unsigned short*)(ws + 54575104);   // w1(kPhix) bf16 / [6144,2048] A for dec g1
    float* Fa  = (float*)(ws + 67158016);                     // v1 f32 (enc mix partner)
    float* Ga  = (float*)(ws + 67158016);                     // [6144,2048] v2 f32 (aliases Fa; Fa dead)
    unsigned short* Gbf = (unsigned short*)(ws + 16826368);   // [6144,2048] v2 bf16 (aliases Abf+Mbf; dead)

    prep_scal<<<8, 256, 0, stream>>>(g1, be1, m1, v1i, b1, a1, c1, bp1,
                                     g3, be3, m3, v3i, b3, a3, c3, bp3);
    prep_w<<<dim3(32, 32, 2), 256, 0, stream>>>(W1, a1, c1, Wt1, bp1,
                                                W3, a3, c3, Wt3, bp3);
    split_x<<<12288, 256, 0, stream>>>(x, o0, o5, Abf);

    // encoder (128^2): v1 = u1 + u2@W1' ; w2 = u2 + v1@W3' ; phiX = mix(v1,w2) fused
    gemm_k<0><<<384, 256, 0, stream>>>(Abf, Wt1, bp1, x, nullptr, Fa, nullptr, Mbf, Dbf, nullptr);
    gemm_k<1><<<384, 256, 0, stream>>>(Mbf, Wt3, bp3, x, nullptr, o1, o6, nullptr, nullptr, Fa);

    // koopman (emits Kbf := w1(kPhix) bf16)
    koop_k<<<3072, 256, 0, stream>>>(o1, kop, o3, Kbf);

    // batched decoders (128^2, 768 blocks = exact 3/CU): v2 = w2 - w1@W3' ; u1 = w1 - v2@W1'
    gemm_k<2><<<768, 256, 0, stream>>>(Dbf, Wt3, bp3, o1, o3, Ga, nullptr, Gbf, nullptr, nullptr);
    gemm_k<3><<<768, 256, 0, stream>>>(Gbf, Wt1, bp1, o1, o3, o2, o4, nullptr, nullptr, Ga);
}